// Round 8
// baseline (371.135 us; speedup 1.0000x reference)
//
#include <hip/hip_runtime.h>

// Corr1d_x: out[n,ch,h,w] = (1/C) * sum_c img1[n,c,h,w] * img2[n,c,h,w + (ch-23)]
// Shapes: img1,img2 [8,256,128,256] fp32; out [8,27,128,256] fp32.
// v8 = v7 with ALL lambdas removed (nested-lambda capture was defeating SROA:
//   v5/v7 spilled acc/pA/pB to scratch even under a sufficient VGPR budget --
//   WRITE_SIZE 516MB vs 28MB ideal). Main-loop body is a macro with literal
//   BUF/FO/A0, expanded 2x per k-iteration and 2x for the chj branches, so
//   every register-array index is a compile-time constant in a flat scope.
// Structure (unchanged from v6/v7): block = one (n,h) row, 4 independent
// waves = {c-half ci} x {ch-half chj}; per-wave private LDS double-buffer;
// barrier-free main loop with issue-then-s_waitcnt vmcnt(8); pair waves
// combine ch-partials via one LDS round at the end.

#define N_      8
#define C_      256
#define H_      128
#define W_      256
#define NCH     27
#define NCQ     128                  // c-channels per wave (half of C)
#define CHUNK   4                    // c-slices per pipeline step
#define NCHUNK  (NCQ / CHUNK)        // 32
#define LROW    288                  // 24 left pad + 256 + 8 right pad
#define PADL    24
#define WLDS    (2 * CHUNK * LROW)   // floats per wave region (dbuf) = 2304
#define SMEM_FLOATS (4 * WLDS)       // 36864 B

__device__ __forceinline__ void async_cp16(const float* g, float* l) {
  __builtin_amdgcn_global_load_lds(
      (const __attribute__((address_space(1))) void*)g,
      (__attribute__((address_space(3))) void*)l,
      16, 0, 0);
}

// One pipeline step: (optionally) issue chunk K+1 (4 LDS-DMA + 4 img1 loads),
// counted-wait so chunk K has landed, then 4x (5 ds_read_b128 + 56 FMA).
// BUF, FO, A0 are literals; CUR/NXT are array names -> all static indexing.
#define BODY(K, BUF, CUR, NXT, MORE, FO, A0)                                   \
  {                                                                            \
    if (MORE) {                                                                \
      const int c0n_ = ((K) + 1) * CHUNK;                                      \
      _Pragma("unroll")                                                        \
      for (int r = 0; r < CHUNK; ++r)                                          \
        async_cp16(i2p + (size_t)(c0n_ + r) * plane,                           \
                   wbase + (((BUF) ^ 1) * CHUNK + r) * LROW + PADL);           \
      _Pragma("unroll")                                                        \
      for (int r = 0; r < CHUNK; ++r)                                          \
        NXT[r] = *(const float4*)(i1p + (size_t)(c0n_ + r) * plane);           \
      asm volatile("s_waitcnt vmcnt(8)" ::: "memory");                         \
    } else {                                                                   \
      asm volatile("s_waitcnt vmcnt(0)" ::: "memory");                         \
    }                                                                          \
    _Pragma("unroll")                                                          \
    for (int r = 0; r < CHUNK; ++r) {                                          \
      const float4 a_ = CUR[r];                                                \
      const float4* lrow_ =                                                    \
          (const float4*)(wbase + ((BUF) * CHUNK + r) * LROW + w0 + (A0));     \
      float f_[20];                                                            \
      _Pragma("unroll")                                                        \
      for (int q = 0; q < 5; ++q) {                                            \
        float4 t_ = lrow_[q];                                                  \
        f_[4*q] = t_.x; f_[4*q+1] = t_.y; f_[4*q+2] = t_.z; f_[4*q+3] = t_.w;  \
      }                                                                        \
      _Pragma("unroll")                                                        \
      for (int c2 = 0; c2 < 14; ++c2) {                                        \
        acc[c2].x = fmaf(a_.x, f_[c2 + (FO)    ], acc[c2].x);                  \
        acc[c2].y = fmaf(a_.y, f_[c2 + (FO) + 1], acc[c2].y);                  \
        acc[c2].z = fmaf(a_.z, f_[c2 + (FO) + 2], acc[c2].z);                  \
        acc[c2].w = fmaf(a_.w, f_[c2 + (FO) + 3], acc[c2].w);                  \
      }                                                                        \
    }                                                                          \
  }

// Full main loop for one chj instantiation (FO/A0 literals).
#define PIPELINE(FO, A0)                                                       \
  {                                                                            \
    float4 pA[CHUNK], pB[CHUNK];                                               \
    _Pragma("unroll")                                                          \
    for (int r = 0; r < CHUNK; ++r)                                            \
      async_cp16(i2p + (size_t)r * plane, wbase + r * LROW + PADL);            \
    _Pragma("unroll")                                                          \
    for (int r = 0; r < CHUNK; ++r)                                            \
      pA[r] = *(const float4*)(i1p + (size_t)r * plane);                       \
    _Pragma("unroll 1")                                                        \
    for (int k = 0; k < NCHUNK; k += 2) {                                      \
      BODY(k,     0, pA, pB, true,               FO, A0)                       \
      BODY(k + 1, 1, pB, pA, (k + 2) < NCHUNK,   FO, A0)                       \
    }                                                                          \
  }

__global__ __launch_bounds__(256, 3)
void corr1d_kernel(const float* __restrict__ img1,
                   const float* __restrict__ img2,
                   float* __restrict__ out) {
  __shared__ __align__(16) float smem[SMEM_FLOATS];

  const int tid  = threadIdx.x;
  const int wv   = tid >> 6;
  const int lane = tid & 63;
  const int w0   = lane << 2;         // lane owns outputs w0..w0+3
  const int ci   = wv & 1;            // c-half
  const int chj  = wv >> 1;           // ch-half: 0 -> ch 0..13, 1 -> ch 14..26

  const int nh = blockIdx.x;          // one (n,h) row per block
  const int n  = nh >> 7;
  const int h  = nh & (H_ - 1);

  float* wbase = &smem[wv * WLDS];

  // Zero ONLY the pad columns of this wave's region (payload is DMA-only;
  // pads [0,24) and [280,288) stay zero forever = shift zero-padding).
  {
    const int row = lane >> 3;             // 8 rows x 32 pad floats
    const int j   = (lane & 7) << 2;       // 0,4,..,28
    const int off = (j < PADL) ? j : j + 256;
    *(float4*)(wbase + row * LROW + off) = make_float4(0.f, 0.f, 0.f, 0.f);
  }

  const size_t plane = (size_t)H_ * W_;
  const float* i1p = img1 + ((size_t)n * C_ + ci * NCQ) * plane
                          + (size_t)h * W_ + w0;
  const float* i2p = img2 + ((size_t)n * C_ + ci * NCQ) * plane
                          + (size_t)h * W_ + w0;   // lane*16B for gload_lds

  float4 acc[14];                     // chj=1: acc[13] is waste, never stored
  #pragma unroll
  for (int ch = 0; ch < 14; ++ch) acc[ch] = make_float4(0.f, 0.f, 0.f, 0.f);

  // img2[w0+j+ch-23] lives at padded slot w0+j+ch+1; ch = chj*14 + c2.
  // Window starts at slot w0+A0 (16B aligned); f index = j + c2 + FO where
  // FO = 1 - A0 + chj*14.  chj=0: A0=0,FO=1 (max f 17); chj=1: A0=12,FO=3.
  if (chj == 0) PIPELINE(1, 0)
  else          PIPELINE(3, 12)

  // Combine c-halves: ci=1 writes partials, ci=0 adds + stores.
  float4* red = (float4*)smem;        // [chj*14 + ch][lane] float4, 28.7KB
  __syncthreads();                    // all staging reads done
  if (ci == 1) {
    #pragma unroll
    for (int ch = 0; ch < 14; ++ch)
      red[(chj * 14 + ch) * 64 + lane] = acc[ch];
  }
  __syncthreads();
  if (ci == 0) {
    const float scale = 1.0f / C_;
    float* op = out + ((size_t)n * NCH + chj * 14) * plane
                    + (size_t)h * W_ + w0;
    if (chj == 0) {
      #pragma unroll
      for (int ch = 0; ch < 14; ++ch) {
        float4 t = red[ch * 64 + lane];
        float4 v = make_float4((acc[ch].x + t.x) * scale,
                               (acc[ch].y + t.y) * scale,
                               (acc[ch].z + t.z) * scale,
                               (acc[ch].w + t.w) * scale);
        *(float4*)(op + (size_t)ch * plane) = v;
      }
    } else {
      #pragma unroll
      for (int ch = 0; ch < 13; ++ch) {   // global ch 14..26
        float4 t = red[(14 + ch) * 64 + lane];
        float4 v = make_float4((acc[ch].x + t.x) * scale,
                               (acc[ch].y + t.y) * scale,
                               (acc[ch].z + t.z) * scale,
                               (acc[ch].w + t.w) * scale);
        *(float4*)(op + (size_t)ch * plane) = v;
      }
    }
  }
}

extern "C" void kernel_launch(void* const* d_in, const int* in_sizes, int n_in,
                              void* d_out, int out_size, void* d_ws, size_t ws_size,
                              hipStream_t stream) {
  const float* img1 = (const float*)d_in[0];
  const float* img2 = (const float*)d_in[1];
  float* out = (float*)d_out;
  corr1d_kernel<<<dim3(N_ * H_), dim3(256), 0, stream>>>(img1, img2, out);
}

// Round 9
// 276.054 us; speedup vs baseline: 1.3444x; 1.3444x over previous
//
#include <hip/hip_runtime.h>

// Corr1d_x: out[n,ch,h,w] = (1/C) * sum_c img1[n,c,h,w] * img2[n,c,h,w + (ch-23)]
// Shapes: img1,img2 [8,256,128,256] fp32; out [8,27,128,256] fp32.
// v9: ZERO-ALLOCA rewrite. v4-v8's 0.5-2.2GB WRITE_SIZE was scratch traffic
//   caused by asm("...":::"memory") waits + unpromoted register arrays: SROA
//   can't split variable-indexed allocas pre-unroll, and the memory clobber
//   then blocks store-to-load forwarding, so acc/pA/pB round-trip scratch
//   every pipeline step. Fix: no arrays at all -- named float4 scalars
//   (A0..A13 acc, q0..q3/r0..r3 img1 prefetch, t0..t4 window) wired by
//   preprocessor-expanded FMA rows with literal indices.
// Structure (validated v6-v8): block = one (n,h) row; 4 independent waves =
//   {c-half ci} x {ch-half chj}; per-wave private LDS double-buffer;
//   barrier-free main loop, issue-then-s_waitcnt vmcnt(8) counted pipeline;
//   pair waves combine partials via one LDS round.

#define N_      8
#define C_      256
#define H_      128
#define W_      256
#define NCH     27
#define NCQ     128                  // c-channels per wave (half of C)
#define CHUNK   4                    // c-slices per pipeline step
#define NCHUNK  (NCQ / CHUNK)        // 32
#define LROW    288                  // 24 left pad + 256 + 8 right pad
#define PADL    24
#define WLDS    (2 * CHUNK * LROW)   // floats per wave region (dbuf) = 2304
#define SMEM_FLOATS (4 * WLDS)       // 36864 B

__device__ __forceinline__ void async_cp16(const float* g, float* l) {
  __builtin_amdgcn_global_load_lds(
      (const __attribute__((address_space(1))) void*)g,
      (__attribute__((address_space(3))) void*)l,
      16, 0, 0);
}

// Window element names (t0..t4 are float4 locals inside COMP)
#define F_0  t0.x
#define F_1  t0.y
#define F_2  t0.z
#define F_3  t0.w
#define F_4  t1.x
#define F_5  t1.y
#define F_6  t1.z
#define F_7  t1.w
#define F_8  t2.x
#define F_9  t2.y
#define F_10 t2.z
#define F_11 t2.w
#define F_12 t3.x
#define F_13 t3.y
#define F_14 t3.z
#define F_15 t3.w
#define F_16 t4.x
#define F_17 t4.y
#define F_18 t4.z
#define F_19 t4.w

#define FMA_ROW(A, Fa, Fb, Fc, Fd)                  \
  A.x = fmaf(a_.x, Fa, A.x); A.y = fmaf(a_.y, Fb, A.y); \
  A.z = fmaf(a_.z, Fc, A.z); A.w = fmaf(a_.w, Fd, A.w);

// chj=0: window starts at slot w0 (A0OFF=0); f index = c2 + 1 + j
#define ROWS_FO1                       \
  FMA_ROW(A0 , F_1 , F_2 , F_3 , F_4 ) \
  FMA_ROW(A1 , F_2 , F_3 , F_4 , F_5 ) \
  FMA_ROW(A2 , F_3 , F_4 , F_5 , F_6 ) \
  FMA_ROW(A3 , F_4 , F_5 , F_6 , F_7 ) \
  FMA_ROW(A4 , F_5 , F_6 , F_7 , F_8 ) \
  FMA_ROW(A5 , F_6 , F_7 , F_8 , F_9 ) \
  FMA_ROW(A6 , F_7 , F_8 , F_9 , F_10) \
  FMA_ROW(A7 , F_8 , F_9 , F_10, F_11) \
  FMA_ROW(A8 , F_9 , F_10, F_11, F_12) \
  FMA_ROW(A9 , F_10, F_11, F_12, F_13) \
  FMA_ROW(A10, F_11, F_12, F_13, F_14) \
  FMA_ROW(A11, F_12, F_13, F_14, F_15) \
  FMA_ROW(A12, F_13, F_14, F_15, F_16) \
  FMA_ROW(A13, F_14, F_15, F_16, F_17)

// chj=1: window starts at slot w0+12 (A0OFF=12); f index = c2 + 3 + j
#define ROWS_FO3                       \
  FMA_ROW(A0 , F_3 , F_4 , F_5 , F_6 ) \
  FMA_ROW(A1 , F_4 , F_5 , F_6 , F_7 ) \
  FMA_ROW(A2 , F_5 , F_6 , F_7 , F_8 ) \
  FMA_ROW(A3 , F_6 , F_7 , F_8 , F_9 ) \
  FMA_ROW(A4 , F_7 , F_8 , F_9 , F_10) \
  FMA_ROW(A5 , F_8 , F_9 , F_10, F_11) \
  FMA_ROW(A6 , F_9 , F_10, F_11, F_12) \
  FMA_ROW(A7 , F_10, F_11, F_12, F_13) \
  FMA_ROW(A8 , F_11, F_12, F_13, F_14) \
  FMA_ROW(A9 , F_12, F_13, F_14, F_15) \
  FMA_ROW(A10, F_13, F_14, F_15, F_16) \
  FMA_ROW(A11, F_14, F_15, F_16, F_17) \
  FMA_ROW(A12, F_15, F_16, F_17, F_18) \
  FMA_ROW(A13, F_16, F_17, F_18, F_19)

// One c-slice: 5x ds_read_b128 window + 56 FMA, all named scalars.
#define COMP(Q, LDSROW, A0OFF, ROWS) {                                        \
    const float4 a_ = Q;                                                      \
    const float4* lrow_ =                                                     \
        (const float4*)(wbase + (LDSROW) * LROW + w0 + (A0OFF));              \
    float4 t0 = lrow_[0]; float4 t1 = lrow_[1]; float4 t2 = lrow_[2];         \
    float4 t3 = lrow_[3]; float4 t4 = lrow_[4];                               \
    ROWS                                                                      \
  }

// Issue 4 LDS-DMA rows for chunk starting at channel C0 into buffer BUF.
#define STAGE(C0, BUF) {                                                      \
    _Pragma("unroll")                                                         \
    for (int r_ = 0; r_ < CHUNK; ++r_)                                        \
      async_cp16(i2p + (size_t)((C0) + r_) * plane,                           \
                 wbase + ((BUF) * CHUNK + r_) * LROW + PADL);                 \
  }

// 4 img1 float4 loads into named destinations.
#define LOADP(P0, P1, P2, P3, C0)                                             \
  P0 = *(const float4*)(i1p + (size_t)((C0) + 0) * plane);                    \
  P1 = *(const float4*)(i1p + (size_t)((C0) + 1) * plane);                    \
  P2 = *(const float4*)(i1p + (size_t)((C0) + 2) * plane);                    \
  P3 = *(const float4*)(i1p + (size_t)((C0) + 3) * plane);

// Pipeline step: issue chunk K+1 (4 DMA + 4 img1), counted-wait chunk K
// landed (8 newest stay in flight), compute 4 c-slices.
#define BODY(K, BUF, C0Q, C1Q, C2Q, C3Q, N0, N1, N2, N3, MORE, A0OFF, ROWS) { \
    if (MORE) {                                                               \
      STAGE(((K) + 1) * CHUNK, (BUF) ^ 1)                                     \
      LOADP(N0, N1, N2, N3, ((K) + 1) * CHUNK)                                \
      asm volatile("s_waitcnt vmcnt(8)" ::: "memory");                        \
    } else {                                                                  \
      asm volatile("s_waitcnt vmcnt(0)" ::: "memory");                        \
    }                                                                         \
    COMP(C0Q, (BUF) * CHUNK + 0, A0OFF, ROWS)                                 \
    COMP(C1Q, (BUF) * CHUNK + 1, A0OFF, ROWS)                                 \
    COMP(C2Q, (BUF) * CHUNK + 2, A0OFF, ROWS)                                 \
    COMP(C3Q, (BUF) * CHUNK + 3, A0OFF, ROWS)                                 \
  }

#define PIPELINE(A0OFF, ROWS) {                                               \
    STAGE(0, 0)                                                               \
    LOADP(q0, q1, q2, q3, 0)                                                  \
    _Pragma("unroll 1")                                                       \
    for (int k = 0; k < NCHUNK; k += 2) {                                     \
      BODY(k,     0, q0,q1,q2,q3, r0,r1,r2,r3, true,             A0OFF, ROWS) \
      BODY(k + 1, 1, r0,r1,r2,r3, q0,q1,q2,q3, (k + 2) < NCHUNK, A0OFF, ROWS) \
    }                                                                         \
  }

__global__ __launch_bounds__(256, 3)
void corr1d_kernel(const float* __restrict__ img1,
                   const float* __restrict__ img2,
                   float* __restrict__ out) {
  __shared__ __align__(16) float smem[SMEM_FLOATS];

  const int tid  = threadIdx.x;
  const int wv   = tid >> 6;
  const int lane = tid & 63;
  const int w0   = lane << 2;         // lane owns outputs w0..w0+3
  const int ci   = wv & 1;            // c-half
  const int chj  = wv >> 1;           // ch-half: 0 -> ch 0..13, 1 -> ch 14..26

  const int nh = blockIdx.x;          // one (n,h) row per block
  const int n  = nh >> 7;
  const int h  = nh & (H_ - 1);

  float* wbase = &smem[wv * WLDS];

  // Zero ONLY the pad columns (payload is DMA-only; pads [0,24) and
  // [280,288) stay zero forever = the shift zero-padding).
  {
    const int row = lane >> 3;             // 8 rows x 32 pad floats
    const int j   = (lane & 7) << 2;       // 0,4,..,28
    const int off = (j < PADL) ? j : j + 256;
    *(float4*)(wbase + row * LROW + off) = make_float4(0.f, 0.f, 0.f, 0.f);
  }

  const size_t plane = (size_t)H_ * W_;
  const float* i1p = img1 + ((size_t)n * C_ + ci * NCQ) * plane
                          + (size_t)h * W_ + w0;
  const float* i2p = img2 + ((size_t)n * C_ + ci * NCQ) * plane
                          + (size_t)h * W_ + w0;   // lane*16B for gload_lds

  float4 A0, A1, A2, A3, A4, A5, A6, A7, A8, A9, A10, A11, A12, A13;
  {
    const float4 z = make_float4(0.f, 0.f, 0.f, 0.f);
    A0=z; A1=z; A2=z; A3=z; A4=z; A5=z; A6=z;
    A7=z; A8=z; A9=z; A10=z; A11=z; A12=z; A13=z;
  }
  float4 q0, q1, q2, q3, r0, r1, r2, r3;

  if (chj == 0) PIPELINE(0,  ROWS_FO1)
  else          PIPELINE(12, ROWS_FO3)

  // Combine c-halves: ci=1 writes partials, ci=0 adds + stores.
  float4* red = (float4*)smem;        // [chj*14 + i][lane] float4, <= 28.7KB
  __syncthreads();                    // all staging reads done
  const int rbase = chj * 14;
  if (ci == 1) {
#define WR(i) red[(rbase + i) * 64 + lane] = A##i;
    WR(0) WR(1) WR(2) WR(3) WR(4) WR(5) WR(6)
    WR(7) WR(8) WR(9) WR(10) WR(11) WR(12) WR(13)
#undef WR
  }
  __syncthreads();
  if (ci == 0) {
    const float scale = 1.0f / C_;
    float* op = out + ((size_t)n * NCH + chj * 14) * plane
                    + (size_t)h * W_ + w0;
#define ST(i)                                                                 \
    { float4 t = red[(rbase + i) * 64 + lane];                                \
      float4 v = make_float4((A##i.x + t.x) * scale, (A##i.y + t.y) * scale,  \
                             (A##i.z + t.z) * scale, (A##i.w + t.w) * scale); \
      *(float4*)(op + (size_t)(i) * plane) = v; }
    ST(0) ST(1) ST(2) ST(3) ST(4) ST(5) ST(6)
    ST(7) ST(8) ST(9) ST(10) ST(11) ST(12)
    if (chj == 0) { ST(13) }          // chj=1 has only 13 channels (14..26)
#undef ST
  }
}

extern "C" void kernel_launch(void* const* d_in, const int* in_sizes, int n_in,
                              void* d_out, int out_size, void* d_ws, size_t ws_size,
                              hipStream_t stream) {
  const float* img1 = (const float*)d_in[0];
  const float* img2 = (const float*)d_in[1];
  float* out = (float*)d_out;
  corr1d_kernel<<<dim3(N_ * H_), dim3(256), 0, stream>>>(img1, img2, out);
}